// Round 3
// baseline (1033.910 us; speedup 1.0000x reference)
//
#include <hip/hip_runtime.h>
#include <stdint.h>

#define BB    2
#define NN    1280
#define KK    48
#define CN    384
#define CE    128
#define CB    192
#define HID   512
#define CO    128
#define MM    (BB*NN*KK)   /* 122880 */
#define CH    (MM/2)       /* trunk chunk rows */

typedef __bf16 bf16x8 __attribute__((ext_vector_type(8)));
typedef float  f32x4  __attribute__((ext_vector_type(4)));
typedef unsigned short u16x8 __attribute__((ext_vector_type(8)));

__device__ __forceinline__ unsigned short f2bf(float f) {
  unsigned int i = __builtin_bit_cast(unsigned int, f);
  unsigned int r = (i + 0x7fffu + ((i >> 16) & 1u)) >> 16;
  return (unsigned short)r;
}
__device__ __forceinline__ float bf2f(unsigned short u) {
  unsigned int v = ((unsigned int)u) << 16;
  return __builtin_bit_cast(float, v);
}

// ---------------- transpose+cast: out_bf16[C][R] = in_f32[R][C] ----------------
__global__ void k_transpose_cast(const float* __restrict__ in,
                                 unsigned short* __restrict__ out,
                                 int R, int C) {
  __shared__ float tile[32][33];
  const int c0 = blockIdx.x * 32, r0 = blockIdx.y * 32;
  const int tx = threadIdx.x, ty = threadIdx.y;
#pragma unroll
  for (int dy = 0; dy < 32; dy += 8)
    tile[ty + dy][tx] = in[(size_t)(r0 + ty + dy) * C + c0 + tx];
  __syncthreads();
#pragma unroll
  for (int dy = 0; dy < 32; dy += 8)
    out[(size_t)(c0 + ty + dy) * R + r0 + tx] = f2bf(tile[tx][ty + dy]);
}

// ---------------- node embed: n = node_emb @ Wi + bi  (all f32, bf16 out) -----
// block = 192 threads, one block per (b,i). Wi is [CN][CB] (untransposed:
// for fixed c, thread t reads Wi[c*CB+t] -> coalesced).
__global__ void k_node(const float* __restrict__ node,
                       const float* __restrict__ Wi,
                       const float* __restrict__ bi,
                       unsigned short* __restrict__ nbuf) {
  __shared__ float row[CN];
  const int blk = blockIdx.x;
  const float* src = node + (size_t)blk * CN;
  for (int c = threadIdx.x; c < CN; c += CB) row[c] = src[c];
  __syncthreads();
  const int t = threadIdx.x;
  float acc = bi[t];
#pragma unroll 8
  for (int c = 0; c < CN; ++c) acc += row[c] * Wi[(size_t)c * CB + t];
  nbuf[(size_t)blk * CB + t] = f2bf(acc);
}

// ---------------- build x = [edge | self | nbr]  (bf16) ----------------
// one wave per edge row; lane l produces 8 bf16 at cols l*8..l*8+7 (16B store)
__global__ void k_build_x(const float* __restrict__ edge,
                          const unsigned short* __restrict__ nbuf,
                          const int* __restrict__ eidx,
                          unsigned short* __restrict__ x) {
  const int w = threadIdx.x >> 6;
  const int l = threadIdx.x & 63;
  const int m = blockIdx.x * 4 + w;
  const int bi = m / KK;   // b*N + i
  uint4 val;
  if (l < 16) {
    // edge_emb cols 0..127, f32 -> bf16
    const float4* e4 = (const float4*)(edge + (size_t)m * CE);
    float4 a = e4[l * 2], b = e4[l * 2 + 1];
    u16x8 p;
    p[0] = f2bf(a.x); p[1] = f2bf(a.y); p[2] = f2bf(a.z); p[3] = f2bf(a.w);
    p[4] = f2bf(b.x); p[5] = f2bf(b.y); p[6] = f2bf(b.z); p[7] = f2bf(b.w);
    val = __builtin_bit_cast(uint4, p);
  } else if (l < 40) {
    val = ((const uint4*)(nbuf + (size_t)bi * CB))[l - 16];
  } else {
    const int b = bi / NN;
    const int e = eidx[m];
    val = ((const uint4*)(nbuf + (size_t)(b * NN + e) * CB))[l - 40];
  }
  ((uint4*)(x + (size_t)m * HID))[l] = val;
}

// ---------------- trunk GEMM: out = relu(A @ W + b) [+ x]  (bf16 in/out) ------
// BM=BN=128, BK=64; 4 waves 2x2, each wave 64x64 via 4x4 MFMA 16x16x32 bf16.
// LDS [128 rows][8 chunks of 16B], chunk XOR-swizzled by row&7.
template <int ADD_X>
__global__ __launch_bounds__(256, 2)
void k_gemm(const unsigned short* __restrict__ A,
            const unsigned short* __restrict__ Wt,   // [512][512] = W^T, bf16
            const float* __restrict__ bias,
            const unsigned short* xres,
            unsigned short* out) {
  __shared__ char lds[32768];
  char* ldsA = lds;
  char* ldsB = lds + 16384;
  const int m0 = blockIdx.x * 128;
  const int n0 = blockIdx.y * 128;
  const int tid = threadIdx.x;
  const int l = tid & 63;
  const int w = tid >> 6;
  const int wm = w >> 1, wn = w & 1;
  const int sr = l >> 3;   // staging row-in-group (== r&7)
  const int pc = l & 7;    // physical chunk

  f32x4 acc[4][4];
#pragma unroll
  for (int i = 0; i < 4; ++i)
#pragma unroll
    for (int j = 0; j < 4; ++j) acc[i][j] = (f32x4){0.f, 0.f, 0.f, 0.f};

  for (int k0 = 0; k0 < HID; k0 += 64) {
    uint4 rga[4], rgb[4];
#pragma unroll
    for (int ii = 0; ii < 4; ++ii) {
      const int i = w * 4 + ii;
      const int r = i * 8 + sr;
      const int lc = pc ^ sr;     // logical chunk landing in physical slot pc
      rga[ii] = *(const uint4*)(A  + (size_t)(m0 + r) * HID + k0 + lc * 8);
      rgb[ii] = *(const uint4*)(Wt + (size_t)(n0 + r) * HID + k0 + lc * 8);
    }
    __syncthreads();
#pragma unroll
    for (int ii = 0; ii < 4; ++ii) {
      const int i = w * 4 + ii;
      *(uint4*)(ldsA + i * 1024 + l * 16) = rga[ii];
      *(uint4*)(ldsB + i * 1024 + l * 16) = rgb[ii];
    }
    __syncthreads();
#pragma unroll
    for (int kk = 0; kk < 2; ++kk) {
      bf16x8 av[4], bv[4];
#pragma unroll
      for (int t = 0; t < 4; ++t) {
        const int ra = wm * 64 + t * 16 + (l & 15);
        const int ca = (kk * 4 + (l >> 4)) ^ (ra & 7);
        av[t] = *(const bf16x8*)(ldsA + ra * 128 + ca * 16);
        const int rb = wn * 64 + t * 16 + (l & 15);
        const int cb = (kk * 4 + (l >> 4)) ^ (rb & 7);
        bv[t] = *(const bf16x8*)(ldsB + rb * 128 + cb * 16);
      }
#pragma unroll
      for (int mt = 0; mt < 4; ++mt)
#pragma unroll
        for (int nt = 0; nt < 4; ++nt)
          acc[mt][nt] = __builtin_amdgcn_mfma_f32_16x16x32_bf16(av[mt], bv[nt], acc[mt][nt], 0, 0, 0);
    }
  }

  const int q = l >> 4, cc = l & 15;
#pragma unroll
  for (int nt = 0; nt < 4; ++nt) {
    const int col = n0 + wn * 64 + nt * 16 + cc;
    const float bvv = bias[col];
#pragma unroll
    for (int mt = 0; mt < 4; ++mt) {
      const int rb = m0 + wm * 64 + mt * 16 + q * 4;
#pragma unroll
      for (int r = 0; r < 4; ++r) {
        float v = acc[mt][nt][r] + bvv;
        v = v > 0.f ? v : 0.f;
        const size_t idx = (size_t)(rb + r) * HID + col;
        if (ADD_X) v += bf2f(xres[idx]);   // a = relu(h1@W2+b2) + x (in-place safe)
        out[idx] = f2bf(v);
      }
    }
  }
}

// ---------------- final GEMM + LayerNorm (f32 output) ----------------
// BM=128, BN=128(=CO), 4 waves 4x1: wave w owns rows w*32..w*32+31, all 128 cols.
__global__ __launch_bounds__(256, 2)
void k_final(const unsigned short* __restrict__ A,     // a = h2 + x, [M][512] bf16
             const unsigned short* __restrict__ Wft,   // [128][512] = Wf^T, bf16
             const float* __restrict__ bias,
             const float* __restrict__ gamma,
             const float* __restrict__ beta,
             float* __restrict__ out) {
  __shared__ char lds[32768];
  char* ldsA = lds;
  char* ldsB = lds + 16384;
  const int m0 = blockIdx.x * 128;
  const int tid = threadIdx.x;
  const int l = tid & 63;
  const int w = tid >> 6;
  const int sr = l >> 3, pc = l & 7;

  f32x4 acc[2][8];
#pragma unroll
  for (int i = 0; i < 2; ++i)
#pragma unroll
    for (int j = 0; j < 8; ++j) acc[i][j] = (f32x4){0.f, 0.f, 0.f, 0.f};

  for (int k0 = 0; k0 < HID; k0 += 64) {
    uint4 rga[4], rgb[4];
#pragma unroll
    for (int ii = 0; ii < 4; ++ii) {
      const int i = w * 4 + ii;
      const int r = i * 8 + sr;
      const int lc = pc ^ sr;
      rga[ii] = *(const uint4*)(A   + (size_t)(m0 + r) * HID + k0 + lc * 8);
      rgb[ii] = *(const uint4*)(Wft + (size_t)r * HID + k0 + lc * 8);
    }
    __syncthreads();
#pragma unroll
    for (int ii = 0; ii < 4; ++ii) {
      const int i = w * 4 + ii;
      *(uint4*)(ldsA + i * 1024 + l * 16) = rga[ii];
      *(uint4*)(ldsB + i * 1024 + l * 16) = rgb[ii];
    }
    __syncthreads();
#pragma unroll
    for (int kk = 0; kk < 2; ++kk) {
      bf16x8 av[2], bv[8];
#pragma unroll
      for (int t = 0; t < 2; ++t) {
        const int ra = w * 32 + t * 16 + (l & 15);
        const int ca = (kk * 4 + (l >> 4)) ^ (ra & 7);
        av[t] = *(const bf16x8*)(ldsA + ra * 128 + ca * 16);
      }
#pragma unroll
      for (int t = 0; t < 8; ++t) {
        const int rb = t * 16 + (l & 15);
        const int cb = (kk * 4 + (l >> 4)) ^ (rb & 7);
        bv[t] = *(const bf16x8*)(ldsB + rb * 128 + cb * 16);
      }
#pragma unroll
      for (int mt = 0; mt < 2; ++mt)
#pragma unroll
        for (int nt = 0; nt < 8; ++nt)
          acc[mt][nt] = __builtin_amdgcn_mfma_f32_16x16x32_bf16(av[mt], bv[nt], acc[mt][nt], 0, 0, 0);
    }
  }

  const int q = l >> 4, cc = l & 15;
  float gg[8], bb[8], bs[8];
#pragma unroll
  for (int j = 0; j < 8; ++j) {
    const int col = j * 16 + cc;
    gg[j] = gamma[col];
    bb[j] = beta[col];
    bs[j] = bias[col];
  }
#pragma unroll
  for (int mt = 0; mt < 2; ++mt) {
#pragma unroll
    for (int r = 0; r < 4; ++r) {
      float s = 0.f, ss = 0.f;
#pragma unroll
      for (int j = 0; j < 8; ++j) {
        const float v = acc[mt][j][r] + bs[j];
        acc[mt][j][r] = v;
        s += v;
        ss += v * v;
      }
#pragma unroll
      for (int mk = 1; mk < 16; mk <<= 1) {
        s  += __shfl_xor(s, mk, 64);
        ss += __shfl_xor(ss, mk, 64);
      }
      const float mu = s * (1.f / 128.f);
      const float var = ss * (1.f / 128.f) - mu * mu;
      const float rstd = rsqrtf(var + 1e-5f);
      const int row = m0 + w * 32 + mt * 16 + q * 4 + r;
#pragma unroll
      for (int j = 0; j < 8; ++j) {
        const float v = (acc[mt][j][r] - mu) * rstd * gg[j] + bb[j];
        out[(size_t)row * CO + j * 16 + cc] = v;
      }
    }
  }
}

// ---------------- workspace layout (bytes) ----------------
// nbuf 983K | Wt1 512K | Wt2 512K | Wft 128K | x 125.8M | h1(half) 62.9M  -> ~192MB
#define O_N    ((size_t)0)
#define O_WT1  ((size_t)0x100000)
#define O_WT2  (O_WT1 + (size_t)0x80000)
#define O_WFT  (O_WT2 + (size_t)0x80000)
#define O_X    ((size_t)0x300000)
#define O_H1   (O_X + (size_t)MM * HID * 2)

extern "C" void kernel_launch(void* const* d_in, const int* in_sizes, int n_in,
                              void* d_out, int out_size, void* d_ws, size_t ws_size,
                              hipStream_t stream) {
  const float* node  = (const float*)d_in[0];
  const float* edge  = (const float*)d_in[1];
  const int*   eidx  = (const int*)d_in[2];
  const float* Wi    = (const float*)d_in[3];
  const float* bi    = (const float*)d_in[4];
  const float* W1    = (const float*)d_in[5];
  const float* b1    = (const float*)d_in[6];
  const float* W2    = (const float*)d_in[7];
  const float* b2    = (const float*)d_in[8];
  const float* Wf    = (const float*)d_in[9];
  const float* bfv   = (const float*)d_in[10];
  const float* gamma = (const float*)d_in[11];
  const float* beta  = (const float*)d_in[12];
  float* out = (float*)d_out;

  char* ws = (char*)d_ws;
  unsigned short* nbuf = (unsigned short*)(ws + O_N);
  unsigned short* Wt1  = (unsigned short*)(ws + O_WT1);
  unsigned short* Wt2  = (unsigned short*)(ws + O_WT2);
  unsigned short* Wft  = (unsigned short*)(ws + O_WFT);
  unsigned short* xbuf = (unsigned short*)(ws + O_X);
  unsigned short* h1   = (unsigned short*)(ws + O_H1);

  // pack weights: W^T in bf16
  k_transpose_cast<<<dim3(HID / 32, HID / 32), dim3(32, 8), 0, stream>>>(W1, Wt1, HID, HID);
  k_transpose_cast<<<dim3(HID / 32, HID / 32), dim3(32, 8), 0, stream>>>(W2, Wt2, HID, HID);
  k_transpose_cast<<<dim3(CO / 32, HID / 32), dim3(32, 8), 0, stream>>>(Wf, Wft, HID, CO);

  // n = node_emb @ Wi + bi  (f32 compute, bf16 out)
  k_node<<<BB * NN, CB, 0, stream>>>(node, Wi, bi, nbuf);

  // x = [edge | self | nbr]  (bf16)
  k_build_x<<<MM / 4, 256, 0, stream>>>(edge, nbuf, eidx, xbuf);

  // trunk in 2 chunks of CH rows (halves peak workspace)
  for (int c = 0; c < 2; ++c) {
    unsigned short* xc = xbuf + (size_t)c * CH * HID;
    // h1 = relu(x @ W1 + b1)
    k_gemm<0><<<dim3(CH / 128, HID / 128), 256, 0, stream>>>(xc, Wt1, b1, nullptr, h1);
    // a = relu(h1 @ W2 + b2) + x   (in-place over x chunk)
    k_gemm<1><<<dim3(CH / 128, HID / 128), 256, 0, stream>>>(h1, Wt2, b2, xc, xc);
  }

  // out = LN(a @ Wf + bf) * gamma + beta  (f32 out)
  k_final<<<MM / 128, 256, 0, stream>>>(xbuf, Wft, bfv, gamma, beta, out);
}

// Round 4
// 415.717 us; speedup vs baseline: 2.4871x; 2.4871x over previous
//
#include <hip/hip_runtime.h>
#include <stdint.h>

#define BB    2
#define NN    1280
#define KK    48
#define CN    384
#define CE    128
#define CB    192
#define HID   512
#define CO    128
#define MM    (BB*NN*KK)   /* 122880 */
#define CH    (MM/2)       /* trunk chunk rows: 61440 -> 480 m-tiles */

typedef __bf16 bf16x8 __attribute__((ext_vector_type(8)));
typedef float  f32x4  __attribute__((ext_vector_type(4)));
typedef unsigned short u16x8 __attribute__((ext_vector_type(8)));

__device__ __forceinline__ unsigned short f2bf(float f) {
  unsigned int i = __builtin_bit_cast(unsigned int, f);
  unsigned int r = (i + 0x7fffu + ((i >> 16) & 1u)) >> 16;
  return (unsigned short)r;
}
__device__ __forceinline__ float bf2f(unsigned short u) {
  unsigned int v = ((unsigned int)u) << 16;
  return __builtin_bit_cast(float, v);
}

// async global->LDS, 16B/lane; LDS dest = wave-uniform base, lane lands at +lane*16
__device__ __forceinline__ void gload_lds16(const void* g, void* l) {
  __builtin_amdgcn_global_load_lds(
      (const __attribute__((address_space(1))) void*)g,
      (__attribute__((address_space(3))) void*)l, 16, 0, 0);
}

// ---------------- transpose+cast: out_bf16[C][R] = in_f32[R][C] ----------------
__global__ void k_transpose_cast(const float* __restrict__ in,
                                 unsigned short* __restrict__ out,
                                 int R, int C) {
  __shared__ float tile[32][33];
  const int c0 = blockIdx.x * 32, r0 = blockIdx.y * 32;
  const int tx = threadIdx.x, ty = threadIdx.y;
#pragma unroll
  for (int dy = 0; dy < 32; dy += 8)
    tile[ty + dy][tx] = in[(size_t)(r0 + ty + dy) * C + c0 + tx];
  __syncthreads();
#pragma unroll
  for (int dy = 0; dy < 32; dy += 8)
    out[(size_t)(c0 + ty + dy) * R + r0 + tx] = f2bf(tile[tx][ty + dy]);
}

// ---------------- node embed: n = node_emb @ Wi + bi  (f32 compute, bf16 out) --
__global__ void k_node(const float* __restrict__ node,
                       const float* __restrict__ Wi,
                       const float* __restrict__ bi,
                       unsigned short* __restrict__ nbuf) {
  __shared__ float row[CN];
  const int blk = blockIdx.x;
  const float* src = node + (size_t)blk * CN;
  for (int c = threadIdx.x; c < CN; c += CB) row[c] = src[c];
  __syncthreads();
  const int t = threadIdx.x;
  float acc = bi[t];
#pragma unroll 8
  for (int c = 0; c < CN; ++c) acc += row[c] * Wi[(size_t)c * CB + t];
  nbuf[(size_t)blk * CB + t] = f2bf(acc);
}

// ---------------- build x = [edge | self | nbr]  (bf16) ----------------
__global__ void k_build_x(const float* __restrict__ edge,
                          const unsigned short* __restrict__ nbuf,
                          const int* __restrict__ eidx,
                          unsigned short* __restrict__ x) {
  const int w = threadIdx.x >> 6;
  const int l = threadIdx.x & 63;
  const int m = blockIdx.x * 4 + w;
  const int bi = m / KK;   // b*N + i
  uint4 val;
  if (l < 16) {
    const float4* e4 = (const float4*)(edge + (size_t)m * CE);
    float4 a = e4[l * 2], b = e4[l * 2 + 1];
    u16x8 p;
    p[0] = f2bf(a.x); p[1] = f2bf(a.y); p[2] = f2bf(a.z); p[3] = f2bf(a.w);
    p[4] = f2bf(b.x); p[5] = f2bf(b.y); p[6] = f2bf(b.z); p[7] = f2bf(b.w);
    val = __builtin_bit_cast(uint4, p);
  } else if (l < 40) {
    val = ((const uint4*)(nbuf + (size_t)bi * CB))[l - 16];
  } else {
    const int b = bi / NN;
    const int e = eidx[m];
    val = ((const uint4*)(nbuf + (size_t)(b * NN + e) * CB))[l - 40];
  }
  ((uint4*)(x + (size_t)m * HID))[l] = val;
}

// ---------------- trunk GEMM: out = relu(A @ W + b) [+ x]  (bf16 in/out) ------
// 1-D grid, XCD-swizzled: xcd = flat&7 gets contiguous m-tiles, 4 n-tiles of one
// m-tile adjacent on the same XCD -> A-tile fetched ~once per XCD.
// BM=BN=128, BK=64; global_load_lds width-16 staging; XOR-swizzled LDS chunks.
// Epilogue: bias+relu in regs -> bf16 tile via LDS -> 16B row-contiguous stores.
template <int ADD_X>
__global__ __launch_bounds__(256, 2)
void k_gemm(const unsigned short* __restrict__ A,
            const unsigned short* __restrict__ Wt,   // [512][512] = W^T, bf16
            const float* __restrict__ bias,
            const unsigned short* xres,
            unsigned short* out) {
  __shared__ char lds[32768];
  char* ldsA = lds;
  char* ldsB = lds + 16384;
  const int flat = blockIdx.x;
  const int xcd = flat & 7;
  const int p = flat >> 3;                 // 0..239
  const int m0 = (xcd * 60 + (p >> 2)) * 128;
  const int n0 = (p & 3) * 128;
  const int tid = threadIdx.x;
  const int l = tid & 63;
  const int w = tid >> 6;
  const int wm = w >> 1, wn = w & 1;
  const int sr = l >> 3;   // staging row-in-group (== row&7)
  const int pc = l & 7;    // physical chunk

  f32x4 acc[4][4];
#pragma unroll
  for (int i = 0; i < 4; ++i)
#pragma unroll
    for (int j = 0; j < 4; ++j) acc[i][j] = (f32x4){0.f, 0.f, 0.f, 0.f};

  for (int k0 = 0; k0 < HID; k0 += 64) {
    __syncthreads();
#pragma unroll
    for (int ii = 0; ii < 4; ++ii) {
      const int i = w * 4 + ii;
      const int r = i * 8 + sr;
      const int lc = pc ^ sr;     // logical chunk landing in physical slot pc
      gload_lds16(A  + (size_t)(m0 + r) * HID + k0 + lc * 8, ldsA + i * 1024);
      gload_lds16(Wt + (size_t)(n0 + r) * HID + k0 + lc * 8, ldsB + i * 1024);
    }
    __syncthreads();
#pragma unroll
    for (int kk = 0; kk < 2; ++kk) {
      bf16x8 av[4], bv[4];
#pragma unroll
      for (int t = 0; t < 4; ++t) {
        const int ra = wm * 64 + t * 16 + (l & 15);
        const int ca = (kk * 4 + (l >> 4)) ^ (ra & 7);
        av[t] = *(const bf16x8*)(ldsA + ra * 128 + ca * 16);
        const int rb = wn * 64 + t * 16 + (l & 15);
        const int cb = (kk * 4 + (l >> 4)) ^ (rb & 7);
        bv[t] = *(const bf16x8*)(ldsB + rb * 128 + cb * 16);
      }
#pragma unroll
      for (int mt = 0; mt < 4; ++mt)
#pragma unroll
        for (int nt = 0; nt < 4; ++nt)
          acc[mt][nt] = __builtin_amdgcn_mfma_f32_16x16x32_bf16(av[mt], bv[nt], acc[mt][nt], 0, 0, 0);
    }
  }

  // ---- epilogue: regs -> bf16 LDS tile (XOR-swizzled) -> 16B vector stores ----
  __syncthreads();
  unsigned short* tile = (unsigned short*)lds;   // 128x128 bf16 = 32KB
  const int q = l >> 4, cc = l & 15;
#pragma unroll
  for (int nt = 0; nt < 4; ++nt) {
    const int col = wn * 64 + nt * 16 + cc;
    const float bvv = bias[n0 + col];
    const int cn = col >> 3, cb = col & 7;
#pragma unroll
    for (int mt = 0; mt < 4; ++mt) {
      const int r0_ = wm * 64 + mt * 16 + q * 4;
#pragma unroll
      for (int r = 0; r < 4; ++r) {
        float v = acc[mt][nt][r] + bvv;
        v = v > 0.f ? v : 0.f;
        const int row = r0_ + r;
        tile[row * 128 + ((cn ^ (row & 7)) << 3) + cb] = f2bf(v);
      }
    }
  }
  __syncthreads();
#pragma unroll
  for (int i = 0; i < 8; ++i) {
    const int c = i * 256 + tid;       // chunk id: 128 rows x 16 chunks
    const int row = c >> 4, cn = c & 15;
    u16x8 vv = *(const u16x8*)(tile + row * 128 + ((cn ^ (row & 7)) << 3));
    const size_t goff = (size_t)(m0 + row) * HID + n0 + cn * 8;
    if (ADD_X) {
      u16x8 xv = *(const u16x8*)(xres + goff);
#pragma unroll
      for (int j = 0; j < 8; ++j) vv[j] = f2bf(bf2f(vv[j]) + bf2f(xv[j]));
    }
    *(u16x8*)(out + goff) = vv;
  }
}

// ---------------- final GEMM + LayerNorm (f32 output) ----------------
__global__ __launch_bounds__(256, 2)
void k_final(const unsigned short* __restrict__ A,     // a = h2 + x, [M][512] bf16
             const unsigned short* __restrict__ Wft,   // [128][512] = Wf^T, bf16
             const float* __restrict__ bias,
             const float* __restrict__ gamma,
             const float* __restrict__ beta,
             float* __restrict__ out) {
  __shared__ char lds[32768];
  char* ldsA = lds;
  char* ldsB = lds + 16384;
  const int m0 = blockIdx.x * 128;
  const int tid = threadIdx.x;
  const int l = tid & 63;
  const int w = tid >> 6;
  const int sr = l >> 3, pc = l & 7;

  f32x4 acc[2][8];
#pragma unroll
  for (int i = 0; i < 2; ++i)
#pragma unroll
    for (int j = 0; j < 8; ++j) acc[i][j] = (f32x4){0.f, 0.f, 0.f, 0.f};

  for (int k0 = 0; k0 < HID; k0 += 64) {
    __syncthreads();
#pragma unroll
    for (int ii = 0; ii < 4; ++ii) {
      const int i = w * 4 + ii;
      const int r = i * 8 + sr;
      const int lc = pc ^ sr;
      gload_lds16(A   + (size_t)(m0 + r) * HID + k0 + lc * 8, ldsA + i * 1024);
      gload_lds16(Wft + (size_t)r * HID + k0 + lc * 8,        ldsB + i * 1024);
    }
    __syncthreads();
#pragma unroll
    for (int kk = 0; kk < 2; ++kk) {
      bf16x8 av[2], bv[8];
#pragma unroll
      for (int t = 0; t < 2; ++t) {
        const int ra = w * 32 + t * 16 + (l & 15);
        const int ca = (kk * 4 + (l >> 4)) ^ (ra & 7);
        av[t] = *(const bf16x8*)(ldsA + ra * 128 + ca * 16);
      }
#pragma unroll
      for (int t = 0; t < 8; ++t) {
        const int rb = t * 16 + (l & 15);
        const int cb = (kk * 4 + (l >> 4)) ^ (rb & 7);
        bv[t] = *(const bf16x8*)(ldsB + rb * 128 + cb * 16);
      }
#pragma unroll
      for (int mt = 0; mt < 2; ++mt)
#pragma unroll
        for (int nt = 0; nt < 8; ++nt)
          acc[mt][nt] = __builtin_amdgcn_mfma_f32_16x16x32_bf16(av[mt], bv[nt], acc[mt][nt], 0, 0, 0);
    }
  }

  const int q = l >> 4, cc = l & 15;
  float gg[8], bb[8], bs[8];
#pragma unroll
  for (int j = 0; j < 8; ++j) {
    const int col = j * 16 + cc;
    gg[j] = gamma[col];
    bb[j] = beta[col];
    bs[j] = bias[col];
  }
#pragma unroll
  for (int mt = 0; mt < 2; ++mt) {
#pragma unroll
    for (int r = 0; r < 4; ++r) {
      float s = 0.f, ss = 0.f;
#pragma unroll
      for (int j = 0; j < 8; ++j) {
        const float v = acc[mt][j][r] + bs[j];
        acc[mt][j][r] = v;
        s += v;
        ss += v * v;
      }
#pragma unroll
      for (int mk = 1; mk < 16; mk <<= 1) {
        s  += __shfl_xor(s, mk, 64);
        ss += __shfl_xor(ss, mk, 64);
      }
      const float mu = s * (1.f / 128.f);
      const float var = ss * (1.f / 128.f) - mu * mu;
      const float rstd = rsqrtf(var + 1e-5f);
      const int row = m0 + w * 32 + mt * 16 + q * 4 + r;
#pragma unroll
      for (int j = 0; j < 8; ++j) {
        const float v = (acc[mt][j][r] - mu) * rstd * gg[j] + bb[j];
        out[(size_t)row * CO + j * 16 + cc] = v;
      }
    }
  }
}

// ---------------- workspace layout (bytes) ----------------
#define O_N    ((size_t)0)
#define O_WT1  ((size_t)0x100000)
#define O_WT2  (O_WT1 + (size_t)0x80000)
#define O_WFT  (O_WT2 + (size_t)0x80000)
#define O_X    ((size_t)0x300000)
#define O_H1   (O_X + (size_t)MM * HID * 2)

extern "C" void kernel_launch(void* const* d_in, const int* in_sizes, int n_in,
                              void* d_out, int out_size, void* d_ws, size_t ws_size,
                              hipStream_t stream) {
  const float* node  = (const float*)d_in[0];
  const float* edge  = (const float*)d_in[1];
  const int*   eidx  = (const int*)d_in[2];
  const float* Wi    = (const float*)d_in[3];
  const float* bi    = (const float*)d_in[4];
  const float* W1    = (const float*)d_in[5];
  const float* b1    = (const float*)d_in[6];
  const float* W2    = (const float*)d_in[7];
  const float* b2    = (const float*)d_in[8];
  const float* Wf    = (const float*)d_in[9];
  const float* bfv   = (const float*)d_in[10];
  const float* gamma = (const float*)d_in[11];
  const float* beta  = (const float*)d_in[12];
  float* out = (float*)d_out;

  char* ws = (char*)d_ws;
  unsigned short* nbuf = (unsigned short*)(ws + O_N);
  unsigned short* Wt1  = (unsigned short*)(ws + O_WT1);
  unsigned short* Wt2  = (unsigned short*)(ws + O_WT2);
  unsigned short* Wft  = (unsigned short*)(ws + O_WFT);
  unsigned short* xbuf = (unsigned short*)(ws + O_X);
  unsigned short* h1   = (unsigned short*)(ws + O_H1);

  // pack weights: W^T in bf16
  k_transpose_cast<<<dim3(HID / 32, HID / 32), dim3(32, 8), 0, stream>>>(W1, Wt1, HID, HID);
  k_transpose_cast<<<dim3(HID / 32, HID / 32), dim3(32, 8), 0, stream>>>(W2, Wt2, HID, HID);
  k_transpose_cast<<<dim3(CO / 32, HID / 32), dim3(32, 8), 0, stream>>>(Wf, Wft, HID, CO);

  // n = node_emb @ Wi + bi
  k_node<<<BB * NN, CB, 0, stream>>>(node, Wi, bi, nbuf);

  // x = [edge | self | nbr]  (bf16)
  k_build_x<<<MM / 4, 256, 0, stream>>>(edge, nbuf, eidx, xbuf);

  // trunk in 2 chunks of CH rows (1920 blocks each, XCD-swizzled inside)
  for (int c = 0; c < 2; ++c) {
    unsigned short* xc = xbuf + (size_t)c * CH * HID;
    k_gemm<0><<<(CH / 128) * 4, 256, 0, stream>>>(xc, Wt1, b1, nullptr, h1);
    k_gemm<1><<<(CH / 128) * 4, 256, 0, stream>>>(h1, Wt2, b2, xc, xc);
  }

  // out = LN(a @ Wf + bf) * gamma + beta  (f32 out)
  k_final<<<MM / 128, 256, 0, stream>>>(xbuf, Wft, bfv, gamma, beta, out);
}

// Round 5
// 385.971 us; speedup vs baseline: 2.6787x; 1.0771x over previous
//
#include <hip/hip_runtime.h>
#include <stdint.h>

#define BB    2
#define NN    1280
#define KK    48
#define CN    384
#define CE    128
#define CB    192
#define HID   512
#define CO    128
#define MM    (BB*NN*KK)   /* 122880 */
#define CH    (MM/2)       /* chunk rows: 61440 = exactly one batch b */

typedef __bf16 bf16x8 __attribute__((ext_vector_type(8)));
typedef float  f32x4  __attribute__((ext_vector_type(4)));
typedef unsigned short u16x8 __attribute__((ext_vector_type(8)));

__device__ __forceinline__ unsigned short f2bf(float f) {
  unsigned int i = __builtin_bit_cast(unsigned int, f);
  unsigned int r = (i + 0x7fffu + ((i >> 16) & 1u)) >> 16;
  return (unsigned short)r;
}
__device__ __forceinline__ float bf2f(unsigned short u) {
  unsigned int v = ((unsigned int)u) << 16;
  return __builtin_bit_cast(float, v);
}

// async global->LDS, 16B/lane; per-lane GLOBAL addresses are fine, LDS dest
// is wave-uniform base + lane*16 (we always use that exact layout).
__device__ __forceinline__ void gload_lds16(const void* g, void* l) {
  __builtin_amdgcn_global_load_lds(
      (const __attribute__((address_space(1))) void*)g,
      (__attribute__((address_space(3))) void*)l, 16, 0, 0);
}

// shared MFMA inner block: 2 k-steps of 4x4 16x16x32 tiles, XOR-swizzled LDS
__device__ __forceinline__ void mfma_tiles(const char* ldsA, const char* ldsB,
                                           int l, int wm, int wn,
                                           f32x4 (&acc)[4][4]) {
#pragma unroll
  for (int kk = 0; kk < 2; ++kk) {
    bf16x8 av[4], bv[4];
#pragma unroll
    for (int t = 0; t < 4; ++t) {
      const int ra = wm * 64 + t * 16 + (l & 15);
      const int ca = (kk * 4 + (l >> 4)) ^ (ra & 7);
      av[t] = *(const bf16x8*)(ldsA + ra * 128 + ca * 16);
      const int rb = wn * 64 + t * 16 + (l & 15);
      const int cb = (kk * 4 + (l >> 4)) ^ (rb & 7);
      bv[t] = *(const bf16x8*)(ldsB + rb * 128 + cb * 16);
    }
#pragma unroll
    for (int mt = 0; mt < 4; ++mt)
#pragma unroll
      for (int nt = 0; nt < 4; ++nt)
        acc[mt][nt] = __builtin_amdgcn_mfma_f32_16x16x32_bf16(av[mt], bv[nt], acc[mt][nt], 0, 0, 0);
  }
}

// ---------------- transpose+cast: out_bf16[C][R] = in_f32[R][C] ----------------
__global__ void k_transpose_cast(const float* __restrict__ in,
                                 unsigned short* __restrict__ out,
                                 int R, int C) {
  __shared__ float tile[32][33];
  const int c0 = blockIdx.x * 32, r0 = blockIdx.y * 32;
  const int tx = threadIdx.x, ty = threadIdx.y;
#pragma unroll
  for (int dy = 0; dy < 32; dy += 8)
    tile[ty + dy][tx] = in[(size_t)(r0 + ty + dy) * C + c0 + tx];
  __syncthreads();
#pragma unroll
  for (int dy = 0; dy < 32; dy += 8)
    out[(size_t)(c0 + ty + dy) * R + r0 + tx] = f2bf(tile[tx][ty + dy]);
}

// ---------------- node embed: n = node_emb @ Wi + bi  (f32 compute, bf16 out) --
__global__ void k_node(const float* __restrict__ node,
                       const float* __restrict__ Wi,
                       const float* __restrict__ bi,
                       unsigned short* __restrict__ nbuf) {
  __shared__ float row[CN];
  const int blk = blockIdx.x;
  const float* src = node + (size_t)blk * CN;
  for (int c = threadIdx.x; c < CN; c += CB) row[c] = src[c];
  __syncthreads();
  const int t = threadIdx.x;
  float acc = bi[t];
#pragma unroll 8
  for (int c = 0; c < CN; ++c) acc += row[c] * Wi[(size_t)c * CB + t];
  nbuf[(size_t)blk * CB + t] = f2bf(acc);
}

// ---------------- GEMM1: h1 = relu(x @ W1 + b1), x assembled in-staging -------
// x[m] = [edge f32->bf16 (k<128) | nbuf[m/48] (128<=k<320) | nbuf[b*N+eidx[m]] (k>=320)]
// No 64-col k-window straddles a region boundary.
__global__ __launch_bounds__(256, 2)
void k_gemm1(const float* __restrict__ edge,
             const unsigned short* __restrict__ nbuf,
             const int* __restrict__ eidx,
             const unsigned short* __restrict__ Wt,   // [512][512] = W1^T bf16
             const float* __restrict__ bias,
             unsigned short* __restrict__ out,        // h1 chunk [CH][512]
             int mbase, int b) {
  __shared__ char lds[32768];
  char* ldsA = lds;
  char* ldsB = lds + 16384;
  const int flat = blockIdx.x;
  const int xcd = flat & 7;
  const int p = flat >> 3;
  const int m0 = (xcd * 60 + (p >> 2)) * 128;
  const int n0 = (p & 3) * 128;
  const int tid = threadIdx.x;
  const int l = tid & 63;
  const int w = tid >> 6;
  const int wm = w >> 1, wn = w & 1;
  const int sr = l >> 3, pc = l & 7;
  const int lc = pc ^ sr;   // logical chunk landing at physical slot pc

  // per-staging-row globals (row r = (w*4+ii)*8+sr)
  int rr[4], big[4], nbrg[4];
  size_t mg[4];
#pragma unroll
  for (int ii = 0; ii < 4; ++ii) {
    const int r = (w * 4 + ii) * 8 + sr;
    rr[ii] = r;
    const int m = mbase + m0 + r;
    mg[ii] = (size_t)m;
    big[ii] = m / KK;
    nbrg[ii] = b * NN + eidx[m];
  }

  f32x4 acc[4][4];
#pragma unroll
  for (int i = 0; i < 4; ++i)
#pragma unroll
    for (int j = 0; j < 4; ++j) acc[i][j] = (f32x4){0.f, 0.f, 0.f, 0.f};

#pragma unroll
  for (int k0 = 0; k0 < HID; k0 += 64) {
    uint4 rga[4];
    if (k0 < 128) {   // edge phase: manual f32->bf16 convert into regs
#pragma unroll
      for (int ii = 0; ii < 4; ++ii) {
        const float4* ep = (const float4*)(edge + mg[ii] * CE + k0 + lc * 8);
        float4 x0 = ep[0], x1 = ep[1];
        u16x8 pk;
        pk[0] = f2bf(x0.x); pk[1] = f2bf(x0.y); pk[2] = f2bf(x0.z); pk[3] = f2bf(x0.w);
        pk[4] = f2bf(x1.x); pk[5] = f2bf(x1.y); pk[6] = f2bf(x1.z); pk[7] = f2bf(x1.w);
        rga[ii] = __builtin_bit_cast(uint4, pk);
      }
    }
    __syncthreads();
#pragma unroll
    for (int ii = 0; ii < 4; ++ii) {
      const int i = w * 4 + ii;
      gload_lds16(Wt + (size_t)(n0 + rr[ii]) * HID + k0 + lc * 8, ldsB + i * 1024);
      if (k0 < 128) {
        *(uint4*)(ldsA + i * 1024 + l * 16) = rga[ii];
      } else if (k0 < 320) {
        gload_lds16(nbuf + (size_t)big[ii] * CB + (k0 - 128) + lc * 8, ldsA + i * 1024);
      } else {
        gload_lds16(nbuf + (size_t)nbrg[ii] * CB + (k0 - 320) + lc * 8, ldsA + i * 1024);
      }
    }
    __syncthreads();
    mfma_tiles(ldsA, ldsB, l, wm, wn, acc);
  }

  // epilogue: bias+relu -> bf16 LDS tile -> 16B row-contiguous stores
  __syncthreads();
  unsigned short* tile = (unsigned short*)lds;
  const int q = l >> 4, cc = l & 15;
#pragma unroll
  for (int nt = 0; nt < 4; ++nt) {
    const int col = wn * 64 + nt * 16 + cc;
    const float bvv = bias[n0 + col];
    const int cn = col >> 3, cb = col & 7;
#pragma unroll
    for (int mt = 0; mt < 4; ++mt) {
      const int r0_ = wm * 64 + mt * 16 + q * 4;
#pragma unroll
      for (int r = 0; r < 4; ++r) {
        float v = acc[mt][nt][r] + bvv;
        v = v > 0.f ? v : 0.f;
        const int row = r0_ + r;
        tile[row * 128 + ((cn ^ (row & 7)) << 3) + cb] = f2bf(v);
      }
    }
  }
  __syncthreads();
#pragma unroll
  for (int i = 0; i < 8; ++i) {
    const int c = i * 256 + tid;
    const int row = c >> 4, cn = c & 15;
    u16x8 vv = *(const u16x8*)(tile + row * 128 + ((cn ^ (row & 7)) << 3));
    *(u16x8*)(out + (size_t)(m0 + row) * HID + n0 + cn * 8) = vv;
  }
}

// ---------------- GEMM2: a = relu(h1 @ W2 + b2) + x, x re-gathered in epilogue -
__global__ __launch_bounds__(256, 2)
void k_gemm2(const unsigned short* __restrict__ A,    // h1 chunk
             const unsigned short* __restrict__ Wt,   // W2^T bf16
             const float* __restrict__ bias,
             const float* __restrict__ edge,
             const unsigned short* __restrict__ nbuf,
             const int* __restrict__ eidx,
             unsigned short* __restrict__ out,        // abuf chunk
             int mbase, int b) {
  __shared__ char lds[32768];
  char* ldsA = lds;
  char* ldsB = lds + 16384;
  const int flat = blockIdx.x;
  const int xcd = flat & 7;
  const int p = flat >> 3;
  const int m0 = (xcd * 60 + (p >> 2)) * 128;
  const int n0 = (p & 3) * 128;
  const int tid = threadIdx.x;
  const int l = tid & 63;
  const int w = tid >> 6;
  const int wm = w >> 1, wn = w & 1;
  const int sr = l >> 3, pc = l & 7;
  const int lc = pc ^ sr;

  f32x4 acc[4][4];
#pragma unroll
  for (int i = 0; i < 4; ++i)
#pragma unroll
    for (int j = 0; j < 4; ++j) acc[i][j] = (f32x4){0.f, 0.f, 0.f, 0.f};

#pragma unroll
  for (int k0 = 0; k0 < HID; k0 += 64) {
    __syncthreads();
#pragma unroll
    for (int ii = 0; ii < 4; ++ii) {
      const int i = w * 4 + ii;
      const int r = i * 8 + sr;
      gload_lds16(A  + (size_t)(m0 + r) * HID + k0 + lc * 8, ldsA + i * 1024);
      gload_lds16(Wt + (size_t)(n0 + r) * HID + k0 + lc * 8, ldsB + i * 1024);
    }
    __syncthreads();
    mfma_tiles(ldsA, ldsB, l, wm, wn, acc);
  }

  // epilogue: bias+relu -> LDS tile; store loop re-gathers residual x
  __syncthreads();
  unsigned short* tile = (unsigned short*)lds;
  const int q = l >> 4, cc = l & 15;
#pragma unroll
  for (int nt = 0; nt < 4; ++nt) {
    const int col = wn * 64 + nt * 16 + cc;
    const float bvv = bias[n0 + col];
    const int cn = col >> 3, cb = col & 7;
#pragma unroll
    for (int mt = 0; mt < 4; ++mt) {
      const int r0_ = wm * 64 + mt * 16 + q * 4;
#pragma unroll
      for (int r = 0; r < 4; ++r) {
        float v = acc[mt][nt][r] + bvv;
        v = v > 0.f ? v : 0.f;
        const int row = r0_ + r;
        tile[row * 128 + ((cn ^ (row & 7)) << 3) + cb] = f2bf(v);
      }
    }
  }
  __syncthreads();
#pragma unroll
  for (int i = 0; i < 8; ++i) {
    const int c = i * 256 + tid;
    const int row = c >> 4, cn = c & 15;
    u16x8 vv = *(const u16x8*)(tile + row * 128 + ((cn ^ (row & 7)) << 3));
    const int m = mbase + m0 + row;
    float rv[8];
    if (n0 == 0) {                       // edge cols 0..127 (f32)
      const float4* ep = (const float4*)(edge + (size_t)m * CE + cn * 8);
      float4 x0 = ep[0], x1 = ep[1];
      rv[0] = x0.x; rv[1] = x0.y; rv[2] = x0.z; rv[3] = x0.w;
      rv[4] = x1.x; rv[5] = x1.y; rv[6] = x1.z; rv[7] = x1.w;
    } else if (n0 == 128) {              // self cols 128..255
      u16x8 xv = *(const u16x8*)(nbuf + (size_t)(m / KK) * CB + cn * 8);
#pragma unroll
      for (int j = 0; j < 8; ++j) rv[j] = bf2f(xv[j]);
    } else if (n0 == 256) {              // cols 256..383: self<320, nbr>=320
      u16x8 xv;
      if (cn < 8) {
        xv = *(const u16x8*)(nbuf + (size_t)(m / KK) * CB + 128 + cn * 8);
      } else {
        const int e = eidx[m];
        xv = *(const u16x8*)(nbuf + (size_t)(b * NN + e) * CB + cn * 8 - 64);
      }
#pragma unroll
      for (int j = 0; j < 8; ++j) rv[j] = bf2f(xv[j]);
    } else {                             // nbr cols 384..511
      const int e = eidx[m];
      u16x8 xv = *(const u16x8*)(nbuf + (size_t)(b * NN + e) * CB + 64 + cn * 8);
#pragma unroll
      for (int j = 0; j < 8; ++j) rv[j] = bf2f(xv[j]);
    }
#pragma unroll
    for (int j = 0; j < 8; ++j) vv[j] = f2bf(bf2f(vv[j]) + rv[j]);
    *(u16x8*)(out + (size_t)(m0 + row) * HID + n0 + cn * 8) = vv;
  }
}

// ---------------- final GEMM + LayerNorm (f32 output) ----------------
__global__ __launch_bounds__(256, 2)
void k_final(const unsigned short* __restrict__ A,     // abuf chunk [CH][512]
             const unsigned short* __restrict__ Wft,   // [128][512] = Wf^T bf16
             const float* __restrict__ bias,
             const float* __restrict__ gamma,
             const float* __restrict__ beta,
             float* __restrict__ out) {
  __shared__ char lds[32768];
  char* ldsA = lds;
  char* ldsB = lds + 16384;
  const int m0 = blockIdx.x * 128;
  const int tid = threadIdx.x;
  const int l = tid & 63;
  const int w = tid >> 6;
  const int sr = l >> 3, pc = l & 7;
  const int lc = pc ^ sr;

  f32x4 acc[2][8];
#pragma unroll
  for (int i = 0; i < 2; ++i)
#pragma unroll
    for (int j = 0; j < 8; ++j) acc[i][j] = (f32x4){0.f, 0.f, 0.f, 0.f};

#pragma unroll
  for (int k0 = 0; k0 < HID; k0 += 64) {
    __syncthreads();
#pragma unroll
    for (int ii = 0; ii < 4; ++ii) {
      const int i = w * 4 + ii;
      const int r = i * 8 + sr;
      gload_lds16(A   + (size_t)(m0 + r) * HID + k0 + lc * 8, ldsA + i * 1024);
      gload_lds16(Wft + (size_t)r * HID + k0 + lc * 8,        ldsB + i * 1024);
    }
    __syncthreads();
#pragma unroll
    for (int kk = 0; kk < 2; ++kk) {
      bf16x8 av[2], bv[8];
#pragma unroll
      for (int t = 0; t < 2; ++t) {
        const int ra = w * 32 + t * 16 + (l & 15);
        const int ca = (kk * 4 + (l >> 4)) ^ (ra & 7);
        av[t] = *(const bf16x8*)(ldsA + ra * 128 + ca * 16);
      }
#pragma unroll
      for (int t = 0; t < 8; ++t) {
        const int rb = t * 16 + (l & 15);
        const int cb = (kk * 4 + (l >> 4)) ^ (rb & 7);
        bv[t] = *(const bf16x8*)(ldsB + rb * 128 + cb * 16);
      }
#pragma unroll
      for (int mt = 0; mt < 2; ++mt)
#pragma unroll
        for (int nt = 0; nt < 8; ++nt)
          acc[mt][nt] = __builtin_amdgcn_mfma_f32_16x16x32_bf16(av[mt], bv[nt], acc[mt][nt], 0, 0, 0);
    }
  }

  const int q = l >> 4, cc = l & 15;
  float gg[8], bb[8], bs[8];
#pragma unroll
  for (int j = 0; j < 8; ++j) {
    const int col = j * 16 + cc;
    gg[j] = gamma[col];
    bb[j] = beta[col];
    bs[j] = bias[col];
  }
#pragma unroll
  for (int mt = 0; mt < 2; ++mt) {
#pragma unroll
    for (int r = 0; r < 4; ++r) {
      float s = 0.f, ss = 0.f;
#pragma unroll
      for (int j = 0; j < 8; ++j) {
        const float v = acc[mt][j][r] + bs[j];
        acc[mt][j][r] = v;
        s += v;
        ss += v * v;
      }
#pragma unroll
      for (int mk = 1; mk < 16; mk <<= 1) {
        s  += __shfl_xor(s, mk, 64);
        ss += __shfl_xor(ss, mk, 64);
      }
      const float mu = s * (1.f / 128.f);
      const float var = ss * (1.f / 128.f) - mu * mu;
      const float rstd = rsqrtf(var + 1e-5f);
      const int row = m0 + w * 32 + mt * 16 + q * 4 + r;
#pragma unroll
      for (int j = 0; j < 8; ++j) {
        const float v = (acc[mt][j][r] - mu) * rstd * gg[j] + bb[j];
        out[(size_t)row * CO + j * 16 + cc] = v;
      }
    }
  }
}

// ---------------- workspace layout (bytes) ----------------
// nbuf 983K | Wt1 512K | Wt2 512K | Wft 128K | h1 chunk 63M | abuf chunk 63M
#define O_N    ((size_t)0)
#define O_WT1  ((size_t)0x100000)
#define O_WT2  (O_WT1 + (size_t)0x80000)
#define O_WFT  (O_WT2 + (size_t)0x80000)
#define O_H1   ((size_t)0x300000)
#define O_A    (O_H1 + (size_t)CH * HID * 2)

extern "C" void kernel_launch(void* const* d_in, const int* in_sizes, int n_in,
                              void* d_out, int out_size, void* d_ws, size_t ws_size,
                              hipStream_t stream) {
  const float* node  = (const float*)d_in[0];
  const float* edge  = (const float*)d_in[1];
  const int*   eidx  = (const int*)d_in[2];
  const float* Wi    = (const float*)d_in[3];
  const float* bi    = (const float*)d_in[4];
  const float* W1    = (const float*)d_in[5];
  const float* b1    = (const float*)d_in[6];
  const float* W2    = (const float*)d_in[7];
  const float* b2    = (const float*)d_in[8];
  const float* Wf    = (const float*)d_in[9];
  const float* bfv   = (const float*)d_in[10];
  const float* gamma = (const float*)d_in[11];
  const float* beta  = (const float*)d_in[12];
  float* out = (float*)d_out;

  char* ws = (char*)d_ws;
  unsigned short* nbuf = (unsigned short*)(ws + O_N);
  unsigned short* Wt1  = (unsigned short*)(ws + O_WT1);
  unsigned short* Wt2  = (unsigned short*)(ws + O_WT2);
  unsigned short* Wft  = (unsigned short*)(ws + O_WFT);
  unsigned short* h1   = (unsigned short*)(ws + O_H1);
  unsigned short* abuf = (unsigned short*)(ws + O_A);

  // pack weights: W^T in bf16
  k_transpose_cast<<<dim3(HID / 32, HID / 32), dim3(32, 8), 0, stream>>>(W1, Wt1, HID, HID);
  k_transpose_cast<<<dim3(HID / 32, HID / 32), dim3(32, 8), 0, stream>>>(W2, Wt2, HID, HID);
  k_transpose_cast<<<dim3(CO / 32, HID / 32), dim3(32, 8), 0, stream>>>(Wf, Wft, HID, CO);

  // n = node_emb @ Wi + bi
  k_node<<<BB * NN, CB, 0, stream>>>(node, Wi, bi, nbuf);

  // trunk + final per chunk (chunk == batch b)
  for (int c = 0; c < 2; ++c) {
    k_gemm1<<<(CH / 128) * 4, 256, 0, stream>>>(edge, nbuf, eidx, Wt1, b1, h1, c * CH, c);
    k_gemm2<<<(CH / 128) * 4, 256, 0, stream>>>(h1, Wt2, b2, edge, nbuf, eidx, abuf, c * CH, c);
    k_final<<<CH / 128, 256, 0, stream>>>(abuf, Wft, bfv, gamma, beta, out + (size_t)c * CH * CO);
  }
}